// Round 1
// baseline (395.130 us; speedup 1.0000x reference)
//
#include <hip/hip_runtime.h>

typedef unsigned short ushort_t;
typedef __attribute__((ext_vector_type(8))) __bf16 bf16x8;
typedef __attribute__((ext_vector_type(4))) float f32x4;

// B=32, N=128, INDIM=32, OUTDIM=64
// X: [32][128][128][32] f32; W: [32][64]; bias: [64]; n_nodes: [32] int
// X1t: [32][64][128][128] bf16  (plane [i][k], k contiguous)  -> MFMA A-operand layout
// X2t: [32][64][128][128] bf16  (plane [j][k], k contiguous)  -> MFMA B-operand layout
// Ct : [32][64][128][128] bf16  (plane [i][j]) aliased over X1t
// out: [32][128][128][64] f32

__device__ __forceinline__ ushort_t f32_to_bf16(float v) {
    unsigned ui = __float_as_uint(v);
    ui += 0x7fffu + ((ui >> 16) & 1u);   // RNE (finite values only)
    return (ushort_t)(ui >> 16);
}

// K1: fused Linear + ReLU + mask, writes bf16 plane rows [r][t] (t contiguous).
// K1a: r = i (rstride=4096), t = j (tstride=32)   -> X1t[b,e,i,j=k]
// K1b: r = j (rstride=32),  t = i (tstride=4096)  -> X2t[b,e,j,i=k]
__global__ __launch_bounds__(256) void lin_kernel(
        const float* __restrict__ X, const float* __restrict__ W,
        const float* __restrict__ bias, const int* __restrict__ n_nodes,
        ushort_t* __restrict__ Out, int rstride, int tstride) {
    __shared__ float sX[128 * 36];             // padded rows: conflict-free frag reads
    const int blk = blockIdx.x;
    const int b = blk >> 7, r = blk & 127;
    const float* Xb = X + (size_t)b * 524288 + (size_t)r * rstride;
    const int u = threadIdx.x;

    // stage X row/column block: 128 t-rows x 32 floats
    #pragma unroll
    for (int it = 0; it < 4; ++it) {
        int idx = it * 256 + u;                 // 0..1023 float4 chunks
        int t = idx >> 3, c = idx & 7;
        float4 v = *(const float4*)(Xb + (size_t)t * tstride + c * 4);
        *(float4*)(sX + t * 36 + c * 4) = v;
    }

    const int n = n_nodes[b];
    const int e = u >> 2, q = u & 3;
    float w[32];
    #pragma unroll
    for (int d = 0; d < 32; ++d) w[d] = W[d * 64 + e];   // L2-hot broadcast-ish
    const float be = bias[e];
    __syncthreads();

    const bool rin = (r < n);
    ushort_t* outp = Out + ((size_t)(b * 64 + e) * 128 + r) * 128;

    for (int jj = 0; jj < 32; ++jj) {
        const int t = q + (jj << 2);            // rows t, t+1, t+2, t+3 across q: no LDS conflict
        const float* xr = sX + t * 36;
        float acc = be;
        #pragma unroll
        for (int c = 0; c < 8; ++c) {
            float4 xv = *(const float4*)(xr + c * 4);
            acc = fmaf(xv.x, w[c * 4 + 0], acc);
            acc = fmaf(xv.y, w[c * 4 + 1], acc);
            acc = fmaf(xv.z, w[c * 4 + 2], acc);
            acc = fmaf(xv.w, w[c * 4 + 3], acc);
        }
        float v = (rin && t < n) ? fmaxf(acc, 0.f) : 0.f;
        outp[t] = f32_to_bf16(v);
    }
}

// K2: per-(b,e) 128x128x128 bf16 MFMA matmul. Writes Ct (aliases X1t plane - safe:
// this wg stages its own plane to LDS before any store; barrier drains loads).
__global__ __launch_bounds__(256) void mm_kernel(
        const ushort_t* __restrict__ X1t, const ushort_t* __restrict__ X2t,
        ushort_t* __restrict__ Ct) {
    __shared__ ushort_t sA[128 * 128];   // [m][k]
    __shared__ ushort_t sB[128 * 128];   // [n][k]
    const int blk = blockIdx.x;
    const size_t plane = (size_t)blk * 16384;    // blk = b*64+e
    const ushort_t* A = X1t + plane;
    const ushort_t* Bm = X2t + plane;
    const int u = threadIdx.x;

    #pragma unroll
    for (int it = 0; it < 8; ++it) {
        int o = (it * 256 + u) * 8;              // 16B chunks
        *(uint4*)(sA + o) = *(const uint4*)(A + o);
        *(uint4*)(sB + o) = *(const uint4*)(Bm + o);
    }
    __syncthreads();

    const int w = u >> 6, l = u & 63;
    const int quad = l >> 4, lid = l & 15;
    const int wr = (w >> 1) * 64, wc = (w & 1) * 64;
    f32x4 acc[4][4] = {};

    #pragma unroll
    for (int k0 = 0; k0 < 128; k0 += 32) {
        bf16x8 af[4], bfr[4];
        #pragma unroll
        for (int mi = 0; mi < 4; ++mi)
            af[mi] = *(const bf16x8*)(sA + (wr + mi * 16 + lid) * 128 + k0 + quad * 8);
        #pragma unroll
        for (int ni = 0; ni < 4; ++ni)
            bfr[ni] = *(const bf16x8*)(sB + (wc + ni * 16 + lid) * 128 + k0 + quad * 8);
        #pragma unroll
        for (int mi = 0; mi < 4; ++mi)
            #pragma unroll
            for (int ni = 0; ni < 4; ++ni)
                acc[mi][ni] = __builtin_amdgcn_mfma_f32_16x16x32_bf16(
                    af[mi], bfr[ni], acc[mi][ni], 0, 0, 0);
    }

    ushort_t* Cp = Ct + plane;
    #pragma unroll
    for (int mi = 0; mi < 4; ++mi)
        #pragma unroll
        for (int ni = 0; ni < 4; ++ni)
            #pragma unroll
            for (int rg = 0; rg < 4; ++rg) {
                int row = wr + mi * 16 + quad * 4 + rg;   // C/D: row=(lane>>4)*4+reg
                int col = wc + ni * 16 + lid;             //      col=lane&15
                Cp[row * 128 + col] = f32_to_bf16(acc[mi][ni][rg]);
            }
}

// K3: [b][e][t] bf16 -> out[b][t][e] f32. Lane index = t => reads coalesced (128B/line
// exact); per-thread e-contiguous writes merge in L2.
__global__ __launch_bounds__(256) void tr_kernel(
        const ushort_t* __restrict__ Ct, float* __restrict__ out) {
    const int gid = blockIdx.x * 256 + threadIdx.x;   // 0..524287 = b*16384 + t
    const int b = gid >> 14, t = gid & 16383;
    const ushort_t* Cb = Ct + (size_t)b * (64 * 16384) + t;
    float* ob = out + (size_t)gid * 64;
    #pragma unroll
    for (int e = 0; e < 64; e += 2) {
        float v0 = __uint_as_float((unsigned)Cb[(size_t)e * 16384] << 16);
        float v1 = __uint_as_float((unsigned)(Cb[(size_t)(e + 1) * 16384]) << 16);
        *(float2*)(ob + e) = make_float2(v0, v1);
    }
}

extern "C" void kernel_launch(void* const* d_in, const int* in_sizes, int n_in,
                              void* d_out, int out_size, void* d_ws, size_t ws_size,
                              hipStream_t stream) {
    const float* X  = (const float*)d_in[0];
    const float* W1 = (const float*)d_in[1];
    const float* b1 = (const float*)d_in[2];
    const float* W2 = (const float*)d_in[3];
    const float* b2 = (const float*)d_in[4];
    const int* nn   = (const int*)d_in[5];
    float* out = (float*)d_out;

    ushort_t* X1t = (ushort_t*)d_ws;          // 67,108,864 B
    ushort_t* X2t = X1t + 33554432;           // +67,108,864 B  (ws needs 128 MiB)
    ushort_t* Ct  = X1t;                      // alias (per-plane exclusive)

    lin_kernel<<<4096, 256, 0, stream>>>(X, W1, b1, nn, X1t, 4096, 32);  // X1t[b,e,i,k=j]
    lin_kernel<<<4096, 256, 0, stream>>>(X, W2, b2, nn, X2t, 32, 4096);  // X2t[b,e,j,k=i]
    mm_kernel<<<2048, 256, 0, stream>>>(X1t, X2t, Ct);
    tr_kernel<<<2048, 256, 0, stream>>>(Ct, out);
}

// Round 2
// 377.261 us; speedup vs baseline: 1.0474x; 1.0474x over previous
//
#include <hip/hip_runtime.h>

typedef unsigned short ushort_t;
typedef __attribute__((ext_vector_type(8))) __bf16 bf16x8;
typedef __attribute__((ext_vector_type(4))) float f32x4;

// B=32, N=128, INDIM=32, OUTDIM=64
// X: [32][128][128][32] f32; W: [32][64]; bias: [64]; n_nodes: [32] int
// X1t: [32][64][128][128] bf16  plane rows i, k=j contiguous  (MFMA row-major [m][k])
// X2t: [32][64][128][128] bf16  plane rows j, k=i contiguous
// Ct : [32][64][128][128] bf16  plane [i][j], aliases X1t (per-plane exclusive)
// out: [32][128][128][64] f32

__device__ __forceinline__ ushort_t f32_to_bf16(float v) {
    unsigned ui = __float_as_uint(v);
    ui += 0x7fffu + ((ui >> 16) & 1u);   // RNE (finite only)
    return (ushort_t)(ui >> 16);
}

union FragU { bf16x8 f; ushort_t u[8]; };
union Pack4 { ushort_t us[4]; uint2 v; };

// K1: Linear(32->64)+bias+ReLU+mask via one mfma_16x16x32 per 16x16 tile (K=32 exact).
// Block = (b, r). A = X rows t (8 m-tiles of 16), B = W^T rows e (4 n-tiles).
// Out[(b*64+e)*128 + r][t]  (t contiguous). No LDS, no barrier.
// K1a: r=i (rstride=4096), t=j (tstride=32); K1b: r=j (rstride=32), t=i (tstride=4096).
__global__ __launch_bounds__(256) void lin_mfma_kernel(
        const float* __restrict__ X, const float* __restrict__ W,
        const float* __restrict__ bias, const int* __restrict__ n_nodes,
        ushort_t* __restrict__ Out, int rstride, int tstride) {
    const int blk = blockIdx.x;
    const int b = blk >> 7, r = blk & 127;
    const float* Xb = X + (size_t)b * 524288 + (size_t)r * rstride;
    const int u = threadIdx.x;
    const int w = u >> 6, l = u & 63;
    const int quad = l >> 4, lid = l & 15;
    const int n = n_nodes[b];
    const bool rin = (r < n);

    // B-fragments: B[n=e][k=d], lane holds e=ni*16+lid, d=quad*8+j. W is [d][e] (L1-hot).
    FragU bfrag[4];
    float bia[4];
    #pragma unroll
    for (int ni = 0; ni < 4; ++ni) {
        const int e = ni * 16 + lid;
        #pragma unroll
        for (int j = 0; j < 8; ++j)
            bfrag[ni].u[j] = f32_to_bf16(W[(quad * 8 + j) * 64 + e]);
        bia[ni] = bias[e];
    }

    #pragma unroll
    for (int s = 0; s < 2; ++s) {
        const int mt = w * 2 + s;               // m-tile: wave w owns tiles 2w, 2w+1
        const int m = mt * 16 + lid;            // global t row for A-frag
        const float* xr = Xb + (size_t)m * tstride + quad * 8;
        float4 x0 = *(const float4*)xr;
        float4 x1 = *(const float4*)(xr + 4);
        FragU af;
        af.u[0] = f32_to_bf16(x0.x); af.u[1] = f32_to_bf16(x0.y);
        af.u[2] = f32_to_bf16(x0.z); af.u[3] = f32_to_bf16(x0.w);
        af.u[4] = f32_to_bf16(x1.x); af.u[5] = f32_to_bf16(x1.y);
        af.u[6] = f32_to_bf16(x1.z); af.u[7] = f32_to_bf16(x1.w);

        #pragma unroll
        for (int ni = 0; ni < 4; ++ni) {
            f32x4 acc = {};
            acc = __builtin_amdgcn_mfma_f32_16x16x32_bf16(af.f, bfrag[ni].f, acc, 0, 0, 0);
            const int e = ni * 16 + lid;
            const int t0 = mt * 16 + quad * 4;  // C/D: row = quad*4+rg, col = lane&15
            Pack4 pk;
            #pragma unroll
            for (int rg = 0; rg < 4; ++rg) {
                const int t = t0 + rg;
                float v = (rin && t < n) ? fmaxf(acc[rg] + bia[ni], 0.f) : 0.f;
                pk.us[rg] = f32_to_bf16(v);
            }
            *(uint2*)(Out + ((size_t)(b * 64 + e) * 128 + r) * 128 + t0) = pk.v;
        }
    }
}

// K2: per-(b,e) 128x128x128 bf16 MFMA. A=X2t rows j, B=X1t rows i so the C reg index
// runs along j (memory-contiguous) -> 8-B packed stores. LDS rows padded to 136 bf16
// (68 dwords: +4 banks/row -> 2-way = free). Writes Ct aliasing X1t (own plane only,
// staged to LDS before stores).
__global__ __launch_bounds__(256) void mm_kernel(
        const ushort_t* __restrict__ X1t, const ushort_t* __restrict__ X2t,
        ushort_t* __restrict__ Ct) {
    __shared__ ushort_t sA[128 * 136];   // X2t plane: [j][k]
    __shared__ ushort_t sB[128 * 136];   // X1t plane: [i][k]
    const int blk = blockIdx.x;
    const size_t plane = (size_t)blk * 16384;    // blk = b*64+e
    const ushort_t* Aj = X2t + plane;
    const ushort_t* Bi = X1t + plane;
    const int u = threadIdx.x;

    #pragma unroll
    for (int it = 0; it < 8; ++it) {
        int idx = it * 256 + u;                  // 2048 chunks of 8 bf16
        int row = idx >> 4, c = idx & 15;
        *(uint4*)(sA + row * 136 + c * 8) = *(const uint4*)(Aj + (size_t)idx * 8);
        *(uint4*)(sB + row * 136 + c * 8) = *(const uint4*)(Bi + (size_t)idx * 8);
    }
    __syncthreads();

    const int w = u >> 6, l = u & 63;
    const int quad = l >> 4, lid = l & 15;
    const int wj = (w >> 1) * 64, wi = (w & 1) * 64;
    f32x4 acc[4][4] = {};                        // [mj][ni]

    #pragma unroll
    for (int k0 = 0; k0 < 128; k0 += 32) {
        bf16x8 af[4], bfr[4];
        #pragma unroll
        for (int mj = 0; mj < 4; ++mj)
            af[mj] = *(const bf16x8*)(sA + (wj + mj * 16 + lid) * 136 + k0 + quad * 8);
        #pragma unroll
        for (int ni = 0; ni < 4; ++ni)
            bfr[ni] = *(const bf16x8*)(sB + (wi + ni * 16 + lid) * 136 + k0 + quad * 8);
        #pragma unroll
        for (int mj = 0; mj < 4; ++mj)
            #pragma unroll
            for (int ni = 0; ni < 4; ++ni)
                acc[mj][ni] = __builtin_amdgcn_mfma_f32_16x16x32_bf16(
                    af[mj], bfr[ni], acc[mj][ni], 0, 0, 0);
    }

    ushort_t* Cp = Ct + plane;
    #pragma unroll
    for (int mj = 0; mj < 4; ++mj)
        #pragma unroll
        for (int ni = 0; ni < 4; ++ni) {
            const int j0 = wj + mj * 16 + quad * 4;   // C row = j (reg-contiguous)
            const int i  = wi + ni * 16 + lid;        // C col = i
            Pack4 pk;
            #pragma unroll
            for (int rg = 0; rg < 4; ++rg)
                pk.us[rg] = f32_to_bf16(acc[mj][ni][rg]);
            *(uint2*)(Cp + (size_t)i * 128 + j0) = pk.v;
        }
}

// K3: Ct[b][e][t] bf16 -> out[b][t][e] f32. Each thread owns 2 t-rows (one uint per e):
// reads 256 B/wave/instruction fully coalesced; per-thread 512-B contiguous out region,
// float2 stores merged in L2.
__global__ __launch_bounds__(256) void tr_kernel(
        const ushort_t* __restrict__ Ct, float* __restrict__ out) {
    const int gid = blockIdx.x * 256 + threadIdx.x;   // 0..262143 = b*8192 + tp
    const int b = gid >> 13, tp = gid & 8191;
    const int t2 = tp * 2;
    const unsigned* Cb32 = (const unsigned*)(Ct + (size_t)b * 1048576 + t2);
    float* o0 = out + ((size_t)b * 16384 + t2) * 64;
    float* o1 = o0 + 64;
    #pragma unroll
    for (int e = 0; e < 64; e += 2) {
        unsigned va = Cb32[(size_t)e * 8192];
        unsigned vb = Cb32[(size_t)(e + 1) * 8192];
        float2 r0 = make_float2(__uint_as_float(va << 16),
                                __uint_as_float(vb << 16));
        float2 r1 = make_float2(__uint_as_float(va & 0xffff0000u),
                                __uint_as_float(vb & 0xffff0000u));
        *(float2*)(o0 + e) = r0;
        *(float2*)(o1 + e) = r1;
    }
}

extern "C" void kernel_launch(void* const* d_in, const int* in_sizes, int n_in,
                              void* d_out, int out_size, void* d_ws, size_t ws_size,
                              hipStream_t stream) {
    const float* X  = (const float*)d_in[0];
    const float* W1 = (const float*)d_in[1];
    const float* b1 = (const float*)d_in[2];
    const float* W2 = (const float*)d_in[3];
    const float* b2 = (const float*)d_in[4];
    const int* nn   = (const int*)d_in[5];
    float* out = (float*)d_out;

    ushort_t* X1t = (ushort_t*)d_ws;          // 64 MiB
    ushort_t* X2t = X1t + 33554432;           // +64 MiB
    ushort_t* Ct  = X1t;                      // alias (per-plane exclusive in K2)

    lin_mfma_kernel<<<4096, 256, 0, stream>>>(X, W1, b1, nn, X1t, 4096, 32);
    lin_mfma_kernel<<<4096, 256, 0, stream>>>(X, W2, b2, nn, X2t, 32, 4096);
    mm_kernel<<<2048, 256, 0, stream>>>(X1t, X2t, Ct);
    tr_kernel<<<1024, 256, 0, stream>>>(Ct, out);
}

// Round 4
// 285.963 us; speedup vs baseline: 1.3818x; 1.3193x over previous
//
#include <hip/hip_runtime.h>

typedef unsigned short ushort_t;
typedef __attribute__((ext_vector_type(8))) __bf16 bf16x8;
typedef __attribute__((ext_vector_type(4))) float f32x4;

// B=32, N=128, INDIM=32, OUTDIM=64
// X: [32][128][128][32] f32; W: [32][64]; bias: [64]; n_nodes: [32] int
// X1t: [32][64][128][128] bf16  plane rows i, k=j contiguous
// X2t: [32][64][128][128] bf16  plane rows j, k=i contiguous
// Ct : [32][64][128][128] bf16  plane [i][j], aliases X1t (per-plane exclusive)
// out: [32][128][128][64] f32

__device__ __forceinline__ ushort_t f32_to_bf16(float v) {
    unsigned ui = __float_as_uint(v);
    ui += 0x7fffu + ((ui >> 16) & 1u);   // RNE (finite only)
    return (ushort_t)(ui >> 16);
}

union FragU { bf16x8 f; ushort_t u[8]; };
union Pack4 { ushort_t us[4]; uint2 v; };

// K1: Linear(32->64)+bias+ReLU+mask via mfma_16x16x32 (K=32 exact).
// Epilogue: stage [e][t] tile in LDS (pad 136 -> 2-way free), then coalesced
// copy-out (16 x 256-B segments per instr instead of 64 x 8-B scatter).
__global__ __launch_bounds__(256) void lin_mfma_kernel(
        const float* __restrict__ X, const float* __restrict__ W,
        const float* __restrict__ bias, const int* __restrict__ n_nodes,
        ushort_t* __restrict__ Out, int rstride, int tstride) {
    __shared__ ushort_t sO[64 * 136];
    const int blk = blockIdx.x;
    const int b = blk >> 7, r = blk & 127;
    const float* Xb = X + (size_t)b * 524288 + (size_t)r * rstride;
    const int u = threadIdx.x;
    const int w = u >> 6, l = u & 63;
    const int quad = l >> 4, lid = l & 15;
    const int n = n_nodes[b];
    const bool rin = (r < n);

    FragU bfrag[4];
    float bia[4];
    #pragma unroll
    for (int ni = 0; ni < 4; ++ni) {
        const int e = ni * 16 + lid;
        #pragma unroll
        for (int j = 0; j < 8; ++j)
            bfrag[ni].u[j] = f32_to_bf16(W[(quad * 8 + j) * 64 + e]);
        bia[ni] = bias[e];
    }

    #pragma unroll
    for (int s = 0; s < 2; ++s) {
        const int mt = w * 2 + s;               // wave w owns m-tiles 2w, 2w+1
        const int m = mt * 16 + lid;
        const float* xr = Xb + (size_t)m * tstride + quad * 8;
        float4 x0 = *(const float4*)xr;
        float4 x1 = *(const float4*)(xr + 4);
        FragU af;
        af.u[0] = f32_to_bf16(x0.x); af.u[1] = f32_to_bf16(x0.y);
        af.u[2] = f32_to_bf16(x0.z); af.u[3] = f32_to_bf16(x0.w);
        af.u[4] = f32_to_bf16(x1.x); af.u[5] = f32_to_bf16(x1.y);
        af.u[6] = f32_to_bf16(x1.z); af.u[7] = f32_to_bf16(x1.w);

        #pragma unroll
        for (int ni = 0; ni < 4; ++ni) {
            f32x4 acc = {};
            acc = __builtin_amdgcn_mfma_f32_16x16x32_bf16(af.f, bfrag[ni].f, acc, 0, 0, 0);
            const int e = ni * 16 + lid;
            const int t0 = mt * 16 + quad * 4;  // C/D: row=quad*4+rg, col=lane&15
            Pack4 pk;
            #pragma unroll
            for (int rg = 0; rg < 4; ++rg) {
                const int t = t0 + rg;
                float v = (rin && t < n) ? fmaxf(acc[rg] + bia[ni], 0.f) : 0.f;
                pk.us[rg] = f32_to_bf16(v);
            }
            *(uint2*)(sO + e * 136 + t0) = pk.v;
        }
    }
    __syncthreads();
    // copy-out: 64 e-rows x 256 B; thread -> (e = u>>2, 64-B part = u&3)
    {
        const int e = u >> 2, part = u & 3;
        ushort_t* gO = Out + ((size_t)(b * 64 + e) * 128 + r) * 128 + part * 32;
        const ushort_t* sRow = sO + e * 136 + part * 32;
        #pragma unroll
        for (int c = 0; c < 4; ++c)
            *(uint4*)(gO + c * 8) = *(const uint4*)(sRow + c * 8);
    }
}

// K2: per-(b,e) 128x128x128 bf16 MFMA. Frags load DIRECT from global (16x64-B
// transactions/instr, waves dedup via L1/L2; no input LDS, no first barrier ->
// 4 blocks/CU). A=X2t rows j, B=X1t rows i, acc[row=j][col=i]. Epilogue stages
// C[i][j] in LDS then flat coalesced copy-out (uniform b128 bank groups).
__global__ __launch_bounds__(256) void mm_kernel(
        const ushort_t* __restrict__ X1t, const ushort_t* __restrict__ X2t,
        ushort_t* __restrict__ Ct) {
    __shared__ ushort_t sC[128 * 136];
    const int blk = blockIdx.x;
    const size_t plane = (size_t)blk * 16384;    // blk = b*64+e
    const ushort_t* Aj = X2t + plane;
    const ushort_t* Bi = X1t + plane;
    const int u = threadIdx.x;
    const int w = u >> 6, l = u & 63;
    const int quad = l >> 4, lid = l & 15;
    const int wj = (w >> 1) * 64, wi = (w & 1) * 64;
    f32x4 acc[4][4] = {};                        // [mj][ni]

    #pragma unroll
    for (int k0 = 0; k0 < 128; k0 += 32) {
        bf16x8 af[4], bfr[4];
        #pragma unroll
        for (int mj = 0; mj < 4; ++mj)
            af[mj] = *(const bf16x8*)(Aj + (size_t)(wj + mj * 16 + lid) * 128 + k0 + quad * 8);
        #pragma unroll
        for (int ni = 0; ni < 4; ++ni)
            bfr[ni] = *(const bf16x8*)(Bi + (size_t)(wi + ni * 16 + lid) * 128 + k0 + quad * 8);
        #pragma unroll
        for (int mj = 0; mj < 4; ++mj)
            #pragma unroll
            for (int ni = 0; ni < 4; ++ni)
                acc[mj][ni] = __builtin_amdgcn_mfma_f32_16x16x32_bf16(
                    af[mj], bfr[ni], acc[mj][ni], 0, 0, 0);
    }

    #pragma unroll
    for (int mj = 0; mj < 4; ++mj)
        #pragma unroll
        for (int ni = 0; ni < 4; ++ni) {
            const int j0 = wj + mj * 16 + quad * 4;   // C row = j (reg-contiguous)
            const int i  = wi + ni * 16 + lid;        // C col = i
            Pack4 pk;
            #pragma unroll
            for (int rg = 0; rg < 4; ++rg)
                pk.us[rg] = f32_to_bf16(acc[mj][ni][rg]);
            *(uint2*)(sC + i * 136 + j0) = pk.v;
        }
    __syncthreads();
    ushort_t* Cp = Ct + plane;
    #pragma unroll
    for (int it = 0; it < 8; ++it) {
        int idx = it * 256 + u;                  // flat 16-B chunk
        int i = idx >> 4, c = idx & 15;
        *(uint4*)(Cp + (size_t)idx * 8) = *(const uint4*)(sC + i * 136 + c * 8);
    }
}

// K3: block = (b, i). Gather Ct[b][e][i][:] for all 64 e (coalesced 256-B reads)
// into LDS sT[e][j] f32 with row stride 129 (reads 2-way = free), then write
// out[b][i][:][:] as ONE contiguous 32-KB region with float4/lane.
__global__ __launch_bounds__(256) void tr_kernel(
        const ushort_t* __restrict__ Ct, float* __restrict__ out) {
    __shared__ float sT[64 * 129];               // rows of 128 j-floats, stride 129
    const int blk = blockIdx.x;                  // b*128 + i
    const int b = blk >> 7, i = blk & 127;
    const int u = threadIdx.x;
    const ushort_t* Cb = Ct + (size_t)b * 1048576 + (size_t)i * 128;

    #pragma unroll
    for (int it = 0; it < 4; ++it) {
        int idx = it * 256 + u;
        int e = idx >> 4, c = idx & 15;
        uint4 v = *(const uint4*)(Cb + (size_t)e * 16384 + c * 8);
        float* dst = sT + e * 129 + c * 8;
        dst[0] = __uint_as_float(v.x << 16);
        dst[1] = __uint_as_float(v.x & 0xffff0000u);
        dst[2] = __uint_as_float(v.y << 16);
        dst[3] = __uint_as_float(v.y & 0xffff0000u);
        dst[4] = __uint_as_float(v.z << 16);
        dst[5] = __uint_as_float(v.z & 0xffff0000u);
        dst[6] = __uint_as_float(v.w << 16);
        dst[7] = __uint_as_float(v.w & 0xffff0000u);
    }
    __syncthreads();

    float* ob = out + ((size_t)b * 16384 + (size_t)i * 128) * 64;
    #pragma unroll
    for (int it = 0; it < 8; ++it) {
        int idx = it * 256 + u;                  // float4 over flat (j,e)
        int j = idx >> 4, e0 = (idx & 15) * 4;
        float4 vv;
        vv.x = sT[(e0 + 0) * 129 + j];
        vv.y = sT[(e0 + 1) * 129 + j];
        vv.z = sT[(e0 + 2) * 129 + j];
        vv.w = sT[(e0 + 3) * 129 + j];
        *(float4*)(ob + (size_t)idx * 4) = vv;
    }
}

extern "C" void kernel_launch(void* const* d_in, const int* in_sizes, int n_in,
                              void* d_out, int out_size, void* d_ws, size_t ws_size,
                              hipStream_t stream) {
    const float* X  = (const float*)d_in[0];
    const float* W1 = (const float*)d_in[1];
    const float* b1 = (const float*)d_in[2];
    const float* W2 = (const float*)d_in[3];
    const float* b2 = (const float*)d_in[4];
    const int* nn   = (const int*)d_in[5];
    float* out = (float*)d_out;

    ushort_t* X1t = (ushort_t*)d_ws;          // 64 MiB
    ushort_t* X2t = X1t + 33554432;           // +64 MiB
    ushort_t* Ct  = X1t;                      // alias (per-plane exclusive in K2)

    lin_mfma_kernel<<<4096, 256, 0, stream>>>(X, W1, b1, nn, X1t, 4096, 32);
    lin_mfma_kernel<<<4096, 256, 0, stream>>>(X, W2, b2, nn, X2t, 32, 4096);
    mm_kernel<<<2048, 256, 0, stream>>>(X1t, X2t, Ct);
    tr_kernel<<<4096, 256, 0, stream>>>(Ct, out);
}

// Round 5
// 270.530 us; speedup vs baseline: 1.4606x; 1.0570x over previous
//
#include <hip/hip_runtime.h>

typedef unsigned short ushort_t;
typedef __attribute__((ext_vector_type(8))) __bf16 bf16x8;
typedef __attribute__((ext_vector_type(4))) float f32x4;

// B=32, N=128, INDIM=32, OUTDIM=64
// X: [32][128][128][32] f32; W: [32][64]; bias: [64]; n_nodes: [32] int
// X1t: [32][64][128][128] bf16  plane rows i, k=j contiguous
// X2t: [32][64][128][128] bf16  plane rows j, k=i contiguous
// Ct : [32][64][128][128] bf16  plane [i][j], aliases X1t (per-plane exclusive)
// out: [32][128][128][64] f32
// Masked rows (>= n_nodes[b]) are exact bf16 zeros everywhere -> k-loop
// truncation and tile skipping below are bit-identical to the full compute.

__device__ __forceinline__ ushort_t f32_to_bf16(float v) {
    unsigned ui = __float_as_uint(v);
    ui += 0x7fffu + ((ui >> 16) & 1u);   // RNE (finite only)
    return (ushort_t)(ui >> 16);
}

union FragU { bf16x8 f; ushort_t u[8]; };
union Pack4 { ushort_t us[4]; uint2 v; };

// K1 (merged passes): Linear(32->64)+bias+ReLU+mask via mfma_16x16x32.
// Grid 2048: blocks 0..1023 pass A (r=i, t=j contiguous), 1024..2047 pass B
// (r=j, t=i strided). Each block handles 4 consecutive r (W-frags built once;
// pass-B reads become 512-B chunks). r>=n and t-tiles>=n skip loads+MFMA.
__global__ __launch_bounds__(256) void lin_mfma_kernel(
        const float* __restrict__ X,
        const float* __restrict__ W1, const float* __restrict__ b1v,
        const float* __restrict__ W2, const float* __restrict__ b2v,
        const int* __restrict__ n_nodes,
        ushort_t* __restrict__ X1t, ushort_t* __restrict__ X2t) {
    __shared__ ushort_t sO[64 * 136];
    const int blk = blockIdx.x;
    const int pass = blk >> 10;
    const int idx = blk & 1023;
    const int b = idx >> 5, rg = idx & 31;           // r-group of 4
    const float* W    = pass ? W2  : W1;
    const float* bias = pass ? b2v : b1v;
    ushort_t* Out     = pass ? X2t : X1t;
    const int rstride = pass ? 32 : 4096;
    const int tstride = pass ? 4096 : 32;

    const int u = threadIdx.x;
    const int w = u >> 6, l = u & 63;
    const int quad = l >> 4, lid = l & 15;
    const int n = n_nodes[b];

    // B-fragments: B[n=e][k=d], lane holds e=ni*16+lid, d=quad*8+j (L1-hot W).
    FragU bfrag[4];
    float bia[4];
    #pragma unroll
    for (int ni = 0; ni < 4; ++ni) {
        const int e = ni * 16 + lid;
        #pragma unroll
        for (int j = 0; j < 8; ++j)
            bfrag[ni].u[j] = f32_to_bf16(W[(quad * 8 + j) * 64 + e]);
        bia[ni] = bias[e];
    }

    for (int q = 0; q < 4; ++q) {
        const int r = rg * 4 + q;
        const bool rin = (r < n);
        if (rin) {
            const float* Xb = X + (size_t)b * 524288 + (size_t)r * rstride;
            #pragma unroll
            for (int s = 0; s < 2; ++s) {
                const int mt = w * 2 + s;           // wave w owns m-tiles 2w,2w+1
                const int t0b = mt * 16 + quad * 4;
                if (mt * 16 < n) {
                    const int m = mt * 16 + lid;
                    const float* xr = Xb + (size_t)m * tstride + quad * 8;
                    float4 x0 = *(const float4*)xr;
                    float4 x1 = *(const float4*)(xr + 4);
                    FragU af;
                    af.u[0] = f32_to_bf16(x0.x); af.u[1] = f32_to_bf16(x0.y);
                    af.u[2] = f32_to_bf16(x0.z); af.u[3] = f32_to_bf16(x0.w);
                    af.u[4] = f32_to_bf16(x1.x); af.u[5] = f32_to_bf16(x1.y);
                    af.u[6] = f32_to_bf16(x1.z); af.u[7] = f32_to_bf16(x1.w);
                    #pragma unroll
                    for (int ni = 0; ni < 4; ++ni) {
                        f32x4 acc = {};
                        acc = __builtin_amdgcn_mfma_f32_16x16x32_bf16(
                            af.f, bfrag[ni].f, acc, 0, 0, 0);
                        const int e = ni * 16 + lid;
                        Pack4 pk;
                        #pragma unroll
                        for (int rgi = 0; rgi < 4; ++rgi) {
                            const int t = t0b + rgi;
                            float v = (t < n) ? fmaxf(acc[rgi] + bia[ni], 0.f) : 0.f;
                            pk.us[rgi] = f32_to_bf16(v);
                        }
                        *(uint2*)(sO + e * 136 + t0b) = pk.v;
                    }
                } else {
                    Pack4 pk; pk.us[0] = pk.us[1] = pk.us[2] = pk.us[3] = 0;
                    #pragma unroll
                    for (int ni = 0; ni < 4; ++ni)
                        *(uint2*)(sO + (ni * 16 + lid) * 136 + t0b) = pk.v;
                }
            }
        }
        __syncthreads();
        {   // copy-out: 64 e-rows x 256 B; thread -> (e=u>>2, 64-B part=u&3)
            const int e = u >> 2, part = u & 3;
            ushort_t* gO = Out + ((size_t)(b * 64 + e) * 128 + r) * 128 + part * 32;
            if (rin) {
                const ushort_t* sRow = sO + e * 136 + part * 32;
                #pragma unroll
                for (int c = 0; c < 4; ++c)
                    *(uint4*)(gO + c * 8) = *(const uint4*)(sRow + c * 8);
            } else {
                uint4 z = {0, 0, 0, 0};
                #pragma unroll
                for (int c = 0; c < 4; ++c)
                    *(uint4*)(gO + c * 8) = z;
            }
        }
        __syncthreads();
    }
}

// K2: per-(b,e) 128x128x128 bf16 MFMA, direct-from-global frags. k-loop
// truncated at ceil(n/32)*32 (tails are exact zeros); j-tiles/i-tiles >= n skip
// loads+MFMA (acc stays zero -> identical stores). Epilogue stages C[i][j] in
// LDS then flat coalesced copy-out.
__global__ __launch_bounds__(256) void mm_kernel(
        const ushort_t* __restrict__ X1t, const ushort_t* __restrict__ X2t,
        ushort_t* __restrict__ Ct, const int* __restrict__ n_nodes) {
    __shared__ ushort_t sC[128 * 136];
    const int blk = blockIdx.x;
    const size_t plane = (size_t)blk * 16384;        // blk = b*64+e
    const int n = n_nodes[blk >> 6];
    const int kmax = (n + 31) & ~31;
    const ushort_t* Aj = X2t + plane;
    const ushort_t* Bi = X1t + plane;
    const int u = threadIdx.x;
    const int w = u >> 6, l = u & 63;
    const int quad = l >> 4, lid = l & 15;
    const int wj = (w >> 1) * 64, wi = (w & 1) * 64;
    const bool anyA = (wj < n), anyB = (wi < n);
    bool aAct[4], bAct[4];
    #pragma unroll
    for (int mj = 0; mj < 4; ++mj) aAct[mj] = (wj + mj * 16) < n;
    #pragma unroll
    for (int ni = 0; ni < 4; ++ni) bAct[ni] = (wi + ni * 16) < n;
    f32x4 acc[4][4] = {};                            // [mj][ni]

    for (int k0 = 0; k0 < kmax; k0 += 32) {
        bf16x8 af[4], bfr[4];
        #pragma unroll
        for (int mj = 0; mj < 4; ++mj)
            if (aAct[mj] && anyB)
                af[mj] = *(const bf16x8*)(Aj + (size_t)(wj + mj * 16 + lid) * 128 + k0 + quad * 8);
        #pragma unroll
        for (int ni = 0; ni < 4; ++ni)
            if (bAct[ni] && anyA)
                bfr[ni] = *(const bf16x8*)(Bi + (size_t)(wi + ni * 16 + lid) * 128 + k0 + quad * 8);
        #pragma unroll
        for (int mj = 0; mj < 4; ++mj)
            #pragma unroll
            for (int ni = 0; ni < 4; ++ni)
                if (aAct[mj] && bAct[ni])
                    acc[mj][ni] = __builtin_amdgcn_mfma_f32_16x16x32_bf16(
                        af[mj], bfr[ni], acc[mj][ni], 0, 0, 0);
    }

    #pragma unroll
    for (int mj = 0; mj < 4; ++mj)
        #pragma unroll
        for (int ni = 0; ni < 4; ++ni) {
            const int j0 = wj + mj * 16 + quad * 4;  // C row = j (reg-contiguous)
            const int i  = wi + ni * 16 + lid;       // C col = i
            Pack4 pk;
            #pragma unroll
            for (int rg = 0; rg < 4; ++rg)
                pk.us[rg] = f32_to_bf16(acc[mj][ni][rg]);
            *(uint2*)(sC + i * 136 + j0) = pk.v;
        }
    __syncthreads();
    ushort_t* Cp = Ct + plane;
    #pragma unroll
    for (int it = 0; it < 8; ++it) {
        int idx = it * 256 + u;
        int i = idx >> 4, c = idx & 15;
        *(uint4*)(Cp + (size_t)idx * 8) = *(const uint4*)(sC + i * 136 + c * 8);
    }
}

// K3: block = (b, i). i>=n: write 32 KB zeros, no reads. Else gather
// Ct[b][e][i][j<n] (coalesced) into LDS sT[e][j] f32 stride 129, zero-fill
// j-tail chunks, then write out[b][i][:][:] as one contiguous 32-KB region.
__global__ __launch_bounds__(256) void tr_kernel(
        const ushort_t* __restrict__ Ct, float* __restrict__ out,
        const int* __restrict__ n_nodes) {
    __shared__ float sT[64 * 129];
    const int blk = blockIdx.x;                      // b*128 + i
    const int b = blk >> 7, i = blk & 127;
    const int u = threadIdx.x;
    const int n = n_nodes[b];
    float* ob = out + ((size_t)b * 16384 + (size_t)i * 128) * 64;

    if (i >= n) {                                    // block-uniform early-out
        float4 z = {0.f, 0.f, 0.f, 0.f};
        #pragma unroll
        for (int it = 0; it < 8; ++it)
            *(float4*)(ob + (size_t)(it * 256 + u) * 4) = z;
        return;
    }

    const ushort_t* Cb = Ct + (size_t)b * 1048576 + (size_t)i * 128;
    #pragma unroll
    for (int it = 0; it < 4; ++it) {
        int idx = it * 256 + u;
        int e = idx >> 4, c = idx & 15;
        float* dst = sT + e * 129 + c * 8;
        if (c * 8 < n) {
            uint4 v = *(const uint4*)(Cb + (size_t)e * 16384 + c * 8);
            dst[0] = __uint_as_float(v.x << 16);
            dst[1] = __uint_as_float(v.x & 0xffff0000u);
            dst[2] = __uint_as_float(v.y << 16);
            dst[3] = __uint_as_float(v.y & 0xffff0000u);
            dst[4] = __uint_as_float(v.z << 16);
            dst[5] = __uint_as_float(v.z & 0xffff0000u);
            dst[6] = __uint_as_float(v.w << 16);
            dst[7] = __uint_as_float(v.w & 0xffff0000u);
        } else {
            #pragma unroll
            for (int t = 0; t < 8; ++t) dst[t] = 0.f;
        }
    }
    __syncthreads();

    #pragma unroll
    for (int it = 0; it < 8; ++it) {
        int idx = it * 256 + u;                      // float4 over flat (j,e)
        int j = idx >> 4, e0 = (idx & 15) * 4;
        float4 vv;
        vv.x = sT[(e0 + 0) * 129 + j];
        vv.y = sT[(e0 + 1) * 129 + j];
        vv.z = sT[(e0 + 2) * 129 + j];
        vv.w = sT[(e0 + 3) * 129 + j];
        *(float4*)(ob + (size_t)idx * 4) = vv;
    }
}

extern "C" void kernel_launch(void* const* d_in, const int* in_sizes, int n_in,
                              void* d_out, int out_size, void* d_ws, size_t ws_size,
                              hipStream_t stream) {
    const float* X  = (const float*)d_in[0];
    const float* W1 = (const float*)d_in[1];
    const float* b1 = (const float*)d_in[2];
    const float* W2 = (const float*)d_in[3];
    const float* b2 = (const float*)d_in[4];
    const int* nn   = (const int*)d_in[5];
    float* out = (float*)d_out;

    ushort_t* X1t = (ushort_t*)d_ws;          // 64 MiB
    ushort_t* X2t = X1t + 33554432;           // +64 MiB
    ushort_t* Ct  = X1t;                      // alias (per-plane exclusive in K2)

    lin_mfma_kernel<<<2048, 256, 0, stream>>>(X, W1, b1, W2, b2, nn, X1t, X2t);
    mm_kernel<<<2048, 256, 0, stream>>>(X1t, X2t, Ct, nn);
    tr_kernel<<<4096, 256, 0, stream>>>(Ct, out, nn);
}